// Round 2
// 229.119 us; speedup vs baseline: 1.0269x; 1.0269x over previous
//
#include <hip/hip_runtime.h>
#include <math.h>

using f16 = _Float16;
using f16x4 = __attribute__((ext_vector_type(4))) _Float16;
using f16x8 = __attribute__((ext_vector_type(8))) _Float16;
using f32x4 = __attribute__((ext_vector_type(4))) float;

static constexpr int B_ = 2, S_ = 2048, H_ = 1024, NH_ = 16, HD_ = 64;
static constexpr int M_ = B_ * S_;                 // 4096 rows of X
static constexpr size_t SZX = (size_t)M_ * H_;     // 4,194,304 elems
static constexpr size_t SZW = (size_t)H_ * H_;     // 1,048,576 elems
static constexpr float LOG2E = 1.4426950408889634f;

__device__ __forceinline__ f32x4 mfma16(f16x8 a, f16x8 b, f32x4 c) {
    return __builtin_amdgcn_mfma_f32_16x16x32_f16(a, b, c, 0, 0, 0);
}
__device__ __forceinline__ f32x4 vmax4(f32x4 a, f32x4 b) {
    f32x4 r;
#pragma unroll
    for (int j = 0; j < 4; ++j) r[j] = fmaxf(a[j], b[j]);
    return r;
}

// async 16B global -> LDS (wave-uniform LDS base + lane*16)
typedef const __attribute__((address_space(1))) unsigned int* gas_t;
typedef __attribute__((address_space(3))) unsigned int* las_t;
__device__ __forceinline__ void load16_lds(const f16* g, f16* lds_base) {
    __builtin_amdgcn_global_load_lds((gas_t)g, (las_t)lds_base, 16, 0, 0);
}

// ---------------- prep: fp32->fp16 x6 tensors + mask*log2e, one launch -----
__global__ __launch_bounds__(256) void prep_kernel(
    const float* __restrict__ xqf, const float* __restrict__ xkf, const float* __restrict__ xvf,
    const float* __restrict__ wqf, const float* __restrict__ wkf, const float* __restrict__ wvf,
    const float* __restrict__ mask,
    f16* __restrict__ xq, f16* __restrict__ xk, f16* __restrict__ xv,
    f16* __restrict__ wq, f16* __restrict__ wk, f16* __restrict__ wv,
    float* __restrict__ mask_s) {
    constexpr int NX = (int)(SZX / 4);   // 1<<20
    constexpr int NW = (int)(SZW / 4);   // 1<<18
    static_assert(NX == (1 << 20) && NW == (1 << 18), "shift assumptions");
    int i = blockIdx.x * 256 + threadIdx.x;
    const float* src;
    f16* dst;
    int j;
    if (i < 3 * NX) {
        int z = i >> 20;
        j = i & (NX - 1);
        src = z == 0 ? xqf : z == 1 ? xkf : xvf;
        dst = z == 0 ? xq : z == 1 ? xk : xv;
    } else if (i < 3 * NX + 3 * NW) {
        int r = i - 3 * NX;
        int z = r >> 18;
        j = r & (NW - 1);
        src = z == 0 ? wqf : z == 1 ? wkf : wvf;
        dst = z == 0 ? wq : z == 1 ? wk : wv;
    } else {
        int r = i - (3 * NX + 3 * NW);
        if (r < B_ * S_ / 4) {
            f32x4 m = ((const f32x4*)mask)[r];
            ((f32x4*)mask_s)[r] = m * LOG2E;
        }
        return;
    }
    f32x4 v = ((const f32x4*)src)[j];
    f16x4 h;
#pragma unroll
    for (int r = 0; r < 4; ++r) h[r] = (f16)v[r];
    ((f16x4*)dst)[j] = h;
}

// ---------------- merged Q/K/V projection ---------------------------------
// which = blockIdx.x>>3 in {0:q, 1:k, 2:v}.
// q/k path: O^T = W·X^T orientation -> [B,NH,S,HD], q pre-scaled log2e/8.
// v path: X·W^T orientation, transposed permuted out vt[bh][d][s'] with
// s' bit-permutation within 32-groups: p1p0=k1k0, p2=k4, p3=k2, p4=k3.
__global__ __launch_bounds__(256, 2) void proj_kernel(
    const f16* __restrict__ xq, const f16* __restrict__ xk, const f16* __restrict__ xv,
    const f16* __restrict__ wq, const f16* __restrict__ wk, const f16* __restrict__ wv,
    const float* __restrict__ bq, const float* __restrict__ bk, const float* __restrict__ bv,
    f16* __restrict__ q, f16* __restrict__ k, f16* __restrict__ vt) {
    __shared__ alignas(16) f16 sX[128][64];
    __shared__ alignas(16) f16 sW[128][64];
    const int t = threadIdx.x, w = t >> 6, lane = t & 63, c = lane & 15, quad = lane >> 4;
    const int which = blockIdx.x >> 3;
    const int col0 = (blockIdx.x & 7) * 128;
    const int row0 = blockIdx.y * 128;
    const f16* X = which == 0 ? xq : which == 1 ? xk : xv;
    const f16* W = which == 0 ? wq : which == 1 ? wk : wv;
    const int wm = (w & 1) * 64, wn = (w >> 1) * 64;
    f32x4 acc[4][4] = {};

    for (int k0 = 0; k0 < H_; k0 += 64) {
        if (k0) __syncthreads();
#pragma unroll
        for (int i = 0; i < 4; ++i) {
            int r = 8 * w + 32 * i + (lane >> 3);
            int cb = (lane & 7) ^ ((lane >> 3) & 7);
            load16_lds(X + (size_t)(row0 + r) * H_ + k0 + cb * 8, &sX[8 * w + 32 * i][0]);
            load16_lds(W + (size_t)(col0 + r) * H_ + k0 + cb * 8, &sW[8 * w + 32 * i][0]);
        }
        __syncthreads();
        if (which == 2) {
#pragma unroll
            for (int ks = 0; ks < 2; ++ks) {
                const int ph = ((ks * 4 + quad) ^ (c & 7)) * 8;
                f16x8 wf[4], xf[4];
#pragma unroll
                for (int gg = 0; gg < 4; ++gg) {
                    wf[gg] = *(const f16x8*)&sW[wn + gg * 16 + c][ph];
                    xf[gg] = *(const f16x8*)&sX[wm + gg * 16 + c][ph];
                }
#pragma unroll
                for (int mg = 0; mg < 4; ++mg)
#pragma unroll
                    for (int ng = 0; ng < 4; ++ng)
                        acc[mg][ng] = mfma16(xf[mg], wf[ng], acc[mg][ng]);
            }
        } else {
#pragma unroll
            for (int ks = 0; ks < 2; ++ks) {
                const int ph = ((ks * 4 + quad) ^ (c & 7)) * 8;
                f16x8 wf[4], xf[4];
#pragma unroll
                for (int gg = 0; gg < 4; ++gg) {
                    wf[gg] = *(const f16x8*)&sW[wn + gg * 16 + c][ph];
                    xf[gg] = *(const f16x8*)&sX[wm + gg * 16 + c][ph];
                }
#pragma unroll
                for (int mg = 0; mg < 4; ++mg)
#pragma unroll
                    for (int ng = 0; ng < 4; ++ng)
                        acc[mg][ng] = mfma16(wf[ng], xf[mg], acc[mg][ng]);
            }
        }
    }

    if (which < 2) {
        const float* bias = which ? bk : bq;
        f16* O = which ? k : q;
        const float scale = which ? 1.0f : (LOG2E * 0.125f);
#pragma unroll
        for (int ng = 0; ng < 4; ++ng) {
            int col4 = col0 + wn + ng * 16 + quad * 4;
            f32x4 bv_ = *(const f32x4*)(bias + col4);
            int hh = col4 >> 6, d = col4 & 63;
#pragma unroll
            for (int mg = 0; mg < 4; ++mg) {
                int rowg = row0 + wm + mg * 16 + c;
                int bb = rowg >> 11, ss = rowg & (S_ - 1);
                f16x4 ov;
#pragma unroll
                for (int r = 0; r < 4; ++r) ov[r] = (f16)((acc[mg][ng][r] + bv_[r]) * scale);
                *(f16x4*)(O + ((size_t)(bb * NH_ + hh) * S_ + ss) * HD_ + d) = ov;
            }
        }
    } else {
#pragma unroll
        for (int ng = 0; ng < 4; ++ng) {
            int col = col0 + wn + ng * 16 + c;
            float bv_ = bv[col];
            int hh = col >> 6, d = col & 63;
#pragma unroll
            for (int mg = 0; mg < 4; ++mg) {
                int rbase = row0 + wm + mg * 16 + quad * 4;
                int bb = rbase >> 11, ss = rbase & (S_ - 1);
                int sl = ss & 31;   // 4-aligned: k1k0 = 0
                int pp = (ss & ~31) | (((sl >> 4) & 1) << 2) | (((sl >> 2) & 1) << 3) | (((sl >> 3) & 1) << 4);
                f16x4 ov;
#pragma unroll
                for (int r = 0; r < 4; ++r) ov[r] = (f16)(acc[mg][ng][r] + bv_);
                *(f16x4*)(vt + ((size_t)(bb * NH_ + hh) * HD_ + d) * S_ + pp) = ov;
            }
        }
    }
}

// ---------------- flash attention, in-block split-KV ------------------------
// 512 threads = 2 groups x 4 waves. Group g handles keys [g*1024, g*1024+1024)
// in 16 tiles of 64 keys; per-wave 32 q columns. End: LDS (m,l,O) combine.
__global__ __launch_bounds__(512, 4) void attn_kernel(
    const f16* __restrict__ Q, const f16* __restrict__ K,
    const f16* __restrict__ VT, const float* __restrict__ mask_s,
    float* __restrict__ out) {
    // 33 KB: sK[2][64][64] (16KB) | sVT[2][64][64] (16KB) | cml (1KB)
    // combine aliases sK+sVT as cO[128][64] f32 (32KB)
    __shared__ alignas(128) unsigned char smem[33792];
    typedef f16 tile_t[64][64];
    tile_t* sK = (tile_t*)smem;
    tile_t* sVT = (tile_t*)(smem + 16384);
    float* cml = (float*)(smem + 32768);
    float* cO = (float*)smem;

    const int t = threadIdx.x, w = t >> 6, lane = t & 63, c = lane & 15, quad = lane >> 4;
    const int g = w >> 2, ww = w & 3;
    const int qt = blockIdx.x, bh = blockIdx.y;
    const int b = bh >> 4, hh = bh & 15;
    const size_t qkb = (size_t)bh * S_ * HD_;
    const size_t vtb = (size_t)bh * HD_ * S_;

    // Q fragments (registers, whole K-loop)
    f16x8 qf[2][2];
#pragma unroll
    for (int nb = 0; nb < 2; ++nb)
#pragma unroll
        for (int ch = 0; ch < 2; ++ch) {
            int qq = qt * 128 + ww * 32 + nb * 16 + c;
            qf[nb][ch] = *(const f16x8*)(Q + qkb + (size_t)qq * HD_ + ch * 32 + quad * 8);
        }

    // staging addresses (iter-invariant parts); 8 rows/wave per load round
    const int lr = lane >> 3;                  // 0..7
    const int lcb = (lane & 7) ^ (lr & 7);     // XOR-swizzled col-block
    const f16* kbase = K + qkb + (size_t)(8 * ww + lr) * HD_ + lcb * 8;
    const f16* vtbase = VT + vtb + (size_t)(8 * ww + lr) * S_ + lcb * 8;
    const float* mbase = mask_s + b * S_ + g * (S_ / 2);

    f32x4 o[4][2] = {};
    float m_i[2] = {-INFINITY, -INFINITY};
    float l_i[2] = {0.f, 0.f};

    for (int it = 0; it < 16; ++it) {
        const int kt = g * 16 + it;   // global 64-key tile index
        if (it) __syncthreads();
#pragma unroll
        for (int i = 0; i < 2; ++i) {
            load16_lds(kbase + (size_t)(kt * 64 + 32 * i) * HD_, &sK[g][8 * ww + 32 * i][0]);
            load16_lds(vtbase + (size_t)(32 * i) * S_ + kt * 64, &sVT[g][8 * ww + 32 * i][0]);
        }
        // S^T init = scaled mask (accumulator trick)
        f32x4 s[4][2];
#pragma unroll
        for (int mb = 0; mb < 4; ++mb) {
            f32x4 mv = *(const f32x4*)(mbase + it * 64 + mb * 16 + quad * 4);
            s[mb][0] = mv;
            s[mb][1] = mv;
        }
        __syncthreads();

        // S^T[key][q] += K·Q^T
        __builtin_amdgcn_s_setprio(1);
#pragma unroll
        for (int ch = 0; ch < 2; ++ch) {
            const int ph = ((ch * 4 + quad) ^ (c & 7)) * 8;
#pragma unroll
            for (int mb = 0; mb < 4; ++mb) {
                f16x8 ah = *(const f16x8*)&sK[g][mb * 16 + c][ph];
#pragma unroll
                for (int nb = 0; nb < 2; ++nb) s[mb][nb] = mfma16(ah, qf[nb][ch], s[mb][nb]);
            }
        }
        __builtin_amdgcn_s_setprio(0);

        // online softmax (per q-column), P -> registers
        f16x4 pf[4][2];
#pragma unroll
        for (int nb = 0; nb < 2; ++nb) {
            f32x4 tm = vmax4(vmax4(s[0][nb], s[1][nb]), vmax4(s[2][nb], s[3][nb]));
            float rm = fmaxf(fmaxf(tm[0], tm[1]), fmaxf(tm[2], tm[3]));
            rm = fmaxf(rm, __shfl_xor(rm, 16));
            rm = fmaxf(rm, __shfl_xor(rm, 32));
            float mnew = fmaxf(m_i[nb], rm);
            float alpha = exp2f(m_i[nb] - mnew);   // first iter: exp2(-inf)=0
            m_i[nb] = mnew;
            f32x4 psum = {0.f, 0.f, 0.f, 0.f};
#pragma unroll
            for (int mb = 0; mb < 4; ++mb) {
                f32x4 pv;
#pragma unroll
                for (int r = 0; r < 4; ++r) {
                    float p = exp2f(s[mb][nb][r] - mnew);
                    pv[r] = p;
                    pf[mb][nb][r] = (f16)p;
                }
                psum += pv;
            }
            float rs = (psum[0] + psum[1]) + (psum[2] + psum[3]);
            rs += __shfl_xor(rs, 16);
            rs += __shfl_xor(rs, 32);
            l_i[nb] = l_i[nb] * alpha + rs;
#pragma unroll
            for (int db = 0; db < 4; ++db) o[db][nb] *= alpha;
        }

        // O^T += V^T·P^T  (A single b128 via permuted VT; P register-resident)
        __builtin_amdgcn_s_setprio(1);
#pragma unroll
        for (int kcc = 0; kcc < 2; ++kcc) {
            const int blk = kcc * 4 + quad;        // 0..7 (64-key tile = 8 blocks)
            const int pblk = (blk ^ c) & 7;
#pragma unroll
            for (int db = 0; db < 4; ++db) {
                f16x8 af = *(const f16x8*)&sVT[g][db * 16 + c][pblk * 8];
#pragma unroll
                for (int nb = 0; nb < 2; ++nb) {
                    f16x8 bf_ = __builtin_shufflevector(pf[2 * kcc][nb], pf[2 * kcc + 1][nb],
                                                        0, 1, 2, 3, 4, 5, 6, 7);
                    o[db][nb] = mfma16(af, bf_, o[db][nb]);
                }
            }
        }
        __builtin_amdgcn_s_setprio(0);
    }

    // ---- combine the two KV-halves via LDS, group 0 writes out ----
    __syncthreads();   // all LDS reads of the loop done; safe to alias
    if (g == 1) {
#pragma unroll
        for (int nb = 0; nb < 2; ++nb) {
            int ql = ww * 32 + nb * 16 + c;
            if (quad == 0) { cml[ql] = m_i[nb]; cml[128 + ql] = l_i[nb]; }
#pragma unroll
            for (int db = 0; db < 4; ++db) {
                int d4 = db * 4 + quad;
                *(f32x4*)&cO[(ql * 16 + (d4 ^ (ql & 15))) << 2] = o[db][nb];
            }
        }
    }
    __syncthreads();
    if (g == 0) {
#pragma unroll
        for (int nb = 0; nb < 2; ++nb) {
            int ql = ww * 32 + nb * 16 + c;
            int qq = qt * 128 + ql;
            float m2 = cml[ql], l2 = cml[128 + ql];
            float mm = fmaxf(m_i[nb], m2);
            float a1 = exp2f(m_i[nb] - mm), a2 = exp2f(m2 - mm);
            float linv = 1.f / (l_i[nb] * a1 + l2 * a2);
#pragma unroll
            for (int db = 0; db < 4; ++db) {
                int d4 = db * 4 + quad;
                f32x4 v2 = *(const f32x4*)&cO[(ql * 16 + (d4 ^ (ql & 15))) << 2];
                f32x4 v = (o[db][nb] * a1 + v2 * a2) * linv;
                *(f32x4*)(out + ((size_t)b * S_ + qq) * H_ + hh * 64 + db * 16 + quad * 4) = v;
            }
        }
    }
}

// ---------------- launch ----------------
extern "C" void kernel_launch(void* const* d_in, const int* in_sizes, int n_in,
                              void* d_out, int out_size, void* d_ws, size_t ws_size,
                              hipStream_t stream) {
    const float* query = (const float*)d_in[0];
    const float* key   = (const float*)d_in[1];
    const float* value = (const float*)d_in[2];
    const float* mask  = (const float*)d_in[3];
    const float* Wq    = (const float*)d_in[4];
    const float* bq    = (const float*)d_in[5];
    const float* Wk    = (const float*)d_in[6];
    const float* bk    = (const float*)d_in[7];
    const float* Wv    = (const float*)d_in[8];
    const float* bv    = (const float*)d_in[9];
    float* out = (float*)d_out;

    f16* p = (f16*)d_ws;
    f16* xq = p; p += SZX; f16* xk = p; p += SZX; f16* xv = p; p += SZX;
    f16* wq = p; p += SZW; f16* wk = p; p += SZW; f16* wv = p; p += SZW;
    f16* q  = p; p += SZX; f16* k  = p; p += SZX; f16* vt = p; p += SZX;
    float* mask_s = (float*)p;   // B_*S_ floats

    const int total = 3 * (int)(SZX / 4) + 3 * (int)(SZW / 4) + (B_ * S_ / 4);
    prep_kernel<<<(total + 255) / 256, 256, 0, stream>>>(
        query, key, value, Wq, Wk, Wv, mask, xq, xk, xv, wq, wk, wv, mask_s);

    dim3 pg(24, M_ / 128);
    proj_kernel<<<pg, 256, 0, stream>>>(xq, xk, xv, wq, wk, wv, bq, bk, bv, q, k, vt);

    dim3 ag(S_ / 128, B_ * NH_);
    attn_kernel<<<ag, 512, 0, stream>>>(q, k, vt, mask_s, out);
}

// Round 4
// 201.823 us; speedup vs baseline: 1.1657x; 1.1352x over previous
//
#include <hip/hip_runtime.h>
#include <math.h>

using f16 = _Float16;
using f16x2 = __attribute__((ext_vector_type(2))) _Float16;
using f16x4 = __attribute__((ext_vector_type(4))) _Float16;
using f16x8 = __attribute__((ext_vector_type(8))) _Float16;
using f32x4 = __attribute__((ext_vector_type(4))) float;
using h16x2 = __attribute__((ext_vector_type(2))) __fp16;

static constexpr int B_ = 2, S_ = 2048, H_ = 1024, NH_ = 16, HD_ = 64;
static constexpr int M_ = B_ * S_;                 // 4096 rows of X
static constexpr size_t SZX = (size_t)M_ * H_;     // 4,194,304 elems
static constexpr size_t SZW = (size_t)H_ * H_;     // 1,048,576 elems
static constexpr float LOG2E = 1.4426950408889634f;

__device__ __forceinline__ f32x4 mfma16(f16x8 a, f16x8 b, f32x4 c) {
    return __builtin_amdgcn_mfma_f32_16x16x32_f16(a, b, c, 0, 0, 0);
}
__device__ __forceinline__ f16x2 cvt_pk(float a, float b) {
    h16x2 r = __builtin_amdgcn_cvt_pkrtz(a, b);
    return __builtin_bit_cast(f16x2, r);
}

// async 16B global -> LDS (wave-uniform LDS base + lane*16)
typedef const __attribute__((address_space(1))) unsigned int* gas_t;
typedef __attribute__((address_space(3))) unsigned int* las_t;
__device__ __forceinline__ void load16_lds(const f16* g, f16* lds_base) {
    __builtin_amdgcn_global_load_lds((gas_t)g, (las_t)lds_base, 16, 0, 0);
}

// ---------------- prep: fp32->fp16 x6 tensors + mask*log2e, one launch -----
__global__ __launch_bounds__(256) void prep_kernel(
    const float* __restrict__ xqf, const float* __restrict__ xkf, const float* __restrict__ xvf,
    const float* __restrict__ wqf, const float* __restrict__ wkf, const float* __restrict__ wvf,
    const float* __restrict__ mask,
    f16* __restrict__ xq, f16* __restrict__ xk, f16* __restrict__ xv,
    f16* __restrict__ wq, f16* __restrict__ wk, f16* __restrict__ wv,
    float* __restrict__ mask_s) {
    constexpr int NX = (int)(SZX / 4);   // 1<<20
    constexpr int NW = (int)(SZW / 4);   // 1<<18
    static_assert(NX == (1 << 20) && NW == (1 << 18), "shift assumptions");
    int i = blockIdx.x * 256 + threadIdx.x;
    const float* src;
    f16* dst;
    int j;
    if (i < 3 * NX) {
        int z = i >> 20;
        j = i & (NX - 1);
        src = z == 0 ? xqf : z == 1 ? xkf : xvf;
        dst = z == 0 ? xq : z == 1 ? xk : xv;
    } else if (i < 3 * NX + 3 * NW) {
        int r = i - 3 * NX;
        int z = r >> 18;
        j = r & (NW - 1);
        src = z == 0 ? wqf : z == 1 ? wkf : wvf;
        dst = z == 0 ? wq : z == 1 ? wk : wv;
    } else {
        int r = i - (3 * NX + 3 * NW);
        if (r < B_ * S_ / 4) {
            f32x4 m = ((const f32x4*)mask)[r];
            ((f32x4*)mask_s)[r] = m * LOG2E;
        }
        return;
    }
    f32x4 v = ((const f32x4*)src)[j];
    f16x4 h;
#pragma unroll
    for (int r = 0; r < 4; ++r) h[r] = (f16)v[r];
    ((f16x4*)dst)[j] = h;
}

// ---------------- merged Q/K/V projection ---------------------------------
// which = blockIdx.x>>3 in {0:q, 1:k, 2:v}.
// q/k path: O^T = W·X^T orientation -> [B,NH,S,HD], q pre-scaled log2e/8.
// v path: X·W^T orientation, transposed permuted out vt[bh][d][s'] with
// s' bit-permutation within 32-groups: p1p0=k1k0, p2=k4, p3=k2, p4=k3.
__global__ __launch_bounds__(256, 2) void proj_kernel(
    const f16* __restrict__ xq, const f16* __restrict__ xk, const f16* __restrict__ xv,
    const f16* __restrict__ wq, const f16* __restrict__ wk, const f16* __restrict__ wv,
    const float* __restrict__ bq, const float* __restrict__ bk, const float* __restrict__ bv,
    f16* __restrict__ q, f16* __restrict__ k, f16* __restrict__ vt) {
    __shared__ alignas(16) f16 sX[128][64];
    __shared__ alignas(16) f16 sW[128][64];
    const int t = threadIdx.x, w = t >> 6, lane = t & 63, c = lane & 15, quad = lane >> 4;
    const int which = blockIdx.x >> 3;
    const int col0 = (blockIdx.x & 7) * 128;
    const int row0 = blockIdx.y * 128;
    const f16* X = which == 0 ? xq : which == 1 ? xk : xv;
    const f16* W = which == 0 ? wq : which == 1 ? wk : wv;
    const int wm = (w & 1) * 64, wn = (w >> 1) * 64;
    f32x4 acc[4][4] = {};

    for (int k0 = 0; k0 < H_; k0 += 64) {
        if (k0) __syncthreads();
#pragma unroll
        for (int i = 0; i < 4; ++i) {
            int r = 8 * w + 32 * i + (lane >> 3);
            int cb = (lane & 7) ^ ((lane >> 3) & 7);
            load16_lds(X + (size_t)(row0 + r) * H_ + k0 + cb * 8, &sX[8 * w + 32 * i][0]);
            load16_lds(W + (size_t)(col0 + r) * H_ + k0 + cb * 8, &sW[8 * w + 32 * i][0]);
        }
        __syncthreads();
        if (which == 2) {
#pragma unroll
            for (int ks = 0; ks < 2; ++ks) {
                const int ph = ((ks * 4 + quad) ^ (c & 7)) * 8;
                f16x8 wf[4], xf[4];
#pragma unroll
                for (int gg = 0; gg < 4; ++gg) {
                    wf[gg] = *(const f16x8*)&sW[wn + gg * 16 + c][ph];
                    xf[gg] = *(const f16x8*)&sX[wm + gg * 16 + c][ph];
                }
#pragma unroll
                for (int mg = 0; mg < 4; ++mg)
#pragma unroll
                    for (int ng = 0; ng < 4; ++ng)
                        acc[mg][ng] = mfma16(xf[mg], wf[ng], acc[mg][ng]);
            }
        } else {
#pragma unroll
            for (int ks = 0; ks < 2; ++ks) {
                const int ph = ((ks * 4 + quad) ^ (c & 7)) * 8;
                f16x8 wf[4], xf[4];
#pragma unroll
                for (int gg = 0; gg < 4; ++gg) {
                    wf[gg] = *(const f16x8*)&sW[wn + gg * 16 + c][ph];
                    xf[gg] = *(const f16x8*)&sX[wm + gg * 16 + c][ph];
                }
#pragma unroll
                for (int mg = 0; mg < 4; ++mg)
#pragma unroll
                    for (int ng = 0; ng < 4; ++ng)
                        acc[mg][ng] = mfma16(wf[ng], xf[mg], acc[mg][ng]);
            }
        }
    }

    if (which < 2) {
        const float* bias = which ? bk : bq;
        f16* O = which ? k : q;
        const float scale = which ? 1.0f : (LOG2E * 0.125f);
#pragma unroll
        for (int ng = 0; ng < 4; ++ng) {
            int col4 = col0 + wn + ng * 16 + quad * 4;
            f32x4 bv_ = *(const f32x4*)(bias + col4);
            int hh = col4 >> 6, d = col4 & 63;
#pragma unroll
            for (int mg = 0; mg < 4; ++mg) {
                int rowg = row0 + wm + mg * 16 + c;
                int bb = rowg >> 11, ss = rowg & (S_ - 1);
                f16x4 ov;
#pragma unroll
                for (int r = 0; r < 4; ++r) ov[r] = (f16)((acc[mg][ng][r] + bv_[r]) * scale);
                *(f16x4*)(O + ((size_t)(bb * NH_ + hh) * S_ + ss) * HD_ + d) = ov;
            }
        }
    } else {
#pragma unroll
        for (int ng = 0; ng < 4; ++ng) {
            int col = col0 + wn + ng * 16 + c;
            float bv_ = bv[col];
            int hh = col >> 6, d = col & 63;
#pragma unroll
            for (int mg = 0; mg < 4; ++mg) {
                int rbase = row0 + wm + mg * 16 + quad * 4;
                int bb = rbase >> 11, ss = rbase & (S_ - 1);
                int sl = ss & 31;   // 4-aligned: k1k0 = 0
                int pp = (ss & ~31) | (((sl >> 4) & 1) << 2) | (((sl >> 2) & 1) << 3) | (((sl >> 3) & 1) << 4);
                f16x4 ov;
#pragma unroll
                for (int r = 0; r < 4; ++r) ov[r] = (f16)(acc[mg][ng][r] + bv_);
                *(f16x4*)(vt + ((size_t)(bb * NH_ + hh) * HD_ + d) * S_ + pp) = ov;
            }
        }
    }
}

// ---------------- flash attention, in-block split-KV, dbuf + counted vmcnt --
// 512 threads = 2 groups x 4 waves. Group g handles keys [g*1024, +1024) in
// 16 tiles of 64. K/V double-buffered; prefetch distance 2 tiles; vmcnt(4)
// (never 0 in steady state); raw s_barrier (no full drains). Softmax:
// native exp2, packed f16 cvt, defer-max (THR=8), l via ones-row MFMA.
__global__ __launch_bounds__(512, 4) void attn_kernel(
    const f16* __restrict__ Q, const f16* __restrict__ K,
    const f16* __restrict__ VT, const float* __restrict__ mask_s,
    float* __restrict__ out) {
    // per-group region (36864 B): sK buf0/buf1 (2x8K) | sVT buf0/buf1 (2x8K)
    //   | maskL 1024 f32 (4K).  +73728: cml 256 f32 (1K).
    // combine phase aliases bytes [0,32768) as cO[128 q][16 swz][4] f32.
    __shared__ alignas(128) unsigned char smem[74752];

    const int t = threadIdx.x, w = t >> 6, lane = t & 63, c = lane & 15, quad = lane >> 4;
    const int g = w >> 2, ww = w & 3;
    const int qt = blockIdx.x, bh = blockIdx.y;
    const int b = bh >> 4, hh = bh & 15;
    const size_t qkb = (size_t)bh * S_ * HD_;
    const size_t vtb = (size_t)bh * HD_ * S_;

    unsigned char* gmem = smem + g * 36864;
    float* maskL = (float*)(gmem + 32768);
    float* cml = (float*)(smem + 73728);
    float* cO = (float*)smem;

    // Q fragments (registers, whole K-loop)
    f16x8 qf[2][2];
#pragma unroll
    for (int nb = 0; nb < 2; ++nb)
#pragma unroll
        for (int ch = 0; ch < 2; ++ch) {
            int qq = qt * 128 + ww * 32 + nb * 16 + c;
            qf[nb][ch] = *(const f16x8*)(Q + qkb + (size_t)qq * HD_ + ch * 32 + quad * 8);
        }

    const int lr = lane >> 3;                  // 0..7
    const int lcb = (lane & 7) ^ lr;           // XOR-swizzled col-block
    const f16* kbase = K + qkb + (size_t)(8 * ww + lr) * HD_ + lcb * 8;
    const f16* vtbase = VT + vtb + (size_t)(8 * ww + lr) * S_ + lcb * 8;

    // stage this group's mask half into LDS (once)
    load16_lds((const f16*)(mask_s + b * S_ + g * 1024 + ww * 256),
               (f16*)(gmem + 32768 + ww * 1024));

    auto stage = [&](int it2, int buf) {
        const int kt2 = g * 16 + it2;
        f16* dK = (f16*)(gmem + buf * 8192) + 8 * ww * 64;
        f16* dV = (f16*)(gmem + 16384 + buf * 8192) + 8 * ww * 64;
        load16_lds(kbase + (size_t)(kt2 * 64) * HD_, dK);
        load16_lds(kbase + (size_t)(kt2 * 64 + 32) * HD_, dK + 32 * 64);
        load16_lds(vtbase + kt2 * 64, dV);
        load16_lds(vtbase + (size_t)32 * S_ + kt2 * 64, dV + 32 * 64);
    };
    stage(0, 0);
    stage(1, 1);
    // drain everything except tile1's 4 staging loads (qf/mask loads are older)
    asm volatile("s_waitcnt vmcnt(4)" ::: "memory");
    asm volatile("s_barrier" ::: "memory");

    // ones-row A fragment for the l accumulator (row d=64 of virtual V^T)
    const f16 one_ = (c == 0) ? (f16)1 : (f16)0;
    const f16x8 af_ones = {one_, one_, one_, one_, one_, one_, one_, one_};

    f32x4 o[5][2] = {};   // db=4 row holds l at (quad==0, elem 0)
    float m_i[2] = {-INFINITY, -INFINITY};

    for (int it = 0; it < 16; ++it) {
        const int cur = it & 1;
        const f16(*sKc)[64] = (const f16(*)[64])(gmem + cur * 8192);
        const f16(*sVc)[64] = (const f16(*)[64])(gmem + 16384 + cur * 8192);

        // S^T init = scaled mask (accumulator trick), from LDS
        f32x4 s[4][2];
#pragma unroll
        for (int mb = 0; mb < 4; ++mb) {
            f32x4 mv = *(const f32x4*)(maskL + it * 64 + mb * 16 + quad * 4);
            s[mb][0] = mv;
            s[mb][1] = mv;
        }

        // S^T[key][q] += K·Q^T
        __builtin_amdgcn_s_setprio(1);
#pragma unroll
        for (int ch = 0; ch < 2; ++ch) {
            const int ph = ((ch * 4 + quad) ^ (c & 7)) * 8;
#pragma unroll
            for (int mb = 0; mb < 4; ++mb) {
                f16x8 ah = *(const f16x8*)&sKc[mb * 16 + c][ph];
                s[mb][0] = mfma16(ah, qf[0][ch], s[mb][0]);
                s[mb][1] = mfma16(ah, qf[1][ch], s[mb][1]);
            }
        }
        __builtin_amdgcn_s_setprio(0);

        // ---- softmax: defer-max fast path ----
        float rloc[2];
#pragma unroll
        for (int nb = 0; nb < 2; ++nb) {   // lane-local max over 16 (max3 tree)
            float a0 = fmaxf(fmaxf(s[0][nb][0], s[0][nb][1]), s[0][nb][2]);
            float a1 = fmaxf(fmaxf(s[0][nb][3], s[1][nb][0]), s[1][nb][1]);
            float a2 = fmaxf(fmaxf(s[1][nb][2], s[1][nb][3]), s[2][nb][0]);
            float a3 = fmaxf(fmaxf(s[2][nb][1], s[2][nb][2]), s[2][nb][3]);
            float a4 = fmaxf(fmaxf(s[3][nb][0], s[3][nb][1]), s[3][nb][2]);
            float b0 = fmaxf(fmaxf(a0, a1), a2);
            float b1 = fmaxf(fmaxf(a3, a4), s[3][nb][3]);
            rloc[nb] = fmaxf(b0, b1);
        }
        if (__any(rloc[0] > m_i[0] + 8.f || rloc[1] > m_i[1] + 8.f)) {
#pragma unroll
            for (int nb = 0; nb < 2; ++nb) {
                float rm = rloc[nb];
                rm = fmaxf(rm, __shfl_xor(rm, 16));
                rm = fmaxf(rm, __shfl_xor(rm, 32));
                float mnew = fmaxf(m_i[nb], rm);
                float alpha = __builtin_amdgcn_exp2f(m_i[nb] - mnew);  // first: 0
                m_i[nb] = mnew;
#pragma unroll
                for (int db = 0; db < 5; ++db) o[db][nb] *= alpha;
            }
        }
        // P = exp2(s - m), bounded by 2^8; packed cvt to f16
        f16x4 pf[4][2];
#pragma unroll
        for (int nb = 0; nb < 2; ++nb) {
            const float m0 = m_i[nb];
#pragma unroll
            for (int mb = 0; mb < 4; ++mb) {
                f16x2 e01 = cvt_pk(__builtin_amdgcn_exp2f(s[mb][nb][0] - m0),
                                   __builtin_amdgcn_exp2f(s[mb][nb][1] - m0));
                f16x2 e23 = cvt_pk(__builtin_amdgcn_exp2f(s[mb][nb][2] - m0),
                                   __builtin_amdgcn_exp2f(s[mb][nb][3] - m0));
                pf[mb][nb] = __builtin_shufflevector(e01, e23, 0, 1, 2, 3);
            }
        }

        // O^T += V^T·P^T ; db=4 is the ones-row -> l accumulates for free
        __builtin_amdgcn_s_setprio(1);
#pragma unroll
        for (int kcc = 0; kcc < 2; ++kcc) {
            const int blk = kcc * 4 + quad;
            const int pblk = (blk ^ c) & 7;
            f16x8 bf0 = __builtin_shufflevector(pf[2 * kcc][0], pf[2 * kcc + 1][0],
                                                0, 1, 2, 3, 4, 5, 6, 7);
            f16x8 bf1 = __builtin_shufflevector(pf[2 * kcc][1], pf[2 * kcc + 1][1],
                                                0, 1, 2, 3, 4, 5, 6, 7);
#pragma unroll
            for (int db = 0; db < 5; ++db) {
                f16x8 af = (db == 4) ? af_ones : *(const f16x8*)&sVc[db * 16 + c][pblk * 8];
                o[db][0] = mfma16(af, bf0, o[db][0]);
                o[db][1] = mfma16(af, bf1, o[db][1]);
            }
        }
        __builtin_amdgcn_s_setprio(0);

        // all waves done reading buf[cur] -> prefetch tile it+2 into it
        asm volatile("s_barrier" ::: "memory");
        if (it < 14) {
            stage(it + 2, cur);
            asm volatile("s_waitcnt vmcnt(4)" ::: "memory");  // tile it+1 landed
        } else {
            asm volatile("s_waitcnt vmcnt(0)" ::: "memory");  // drain tail
        }
        asm volatile("s_barrier" ::: "memory");
    }

    // extract l (held at quad==0 lanes, col c) and broadcast to the wave
    float l_i[2];
    l_i[0] = __shfl(o[4][0][0], c);
    l_i[1] = __shfl(o[4][1][0], c);

    // ---- combine the two KV-halves via LDS, group 0 writes out ----
    if (g == 1) {
#pragma unroll
        for (int nb = 0; nb < 2; ++nb) {
            int ql = ww * 32 + nb * 16 + c;
            if (quad == 0) { cml[ql] = m_i[nb]; cml[128 + ql] = l_i[nb]; }
#pragma unroll
            for (int db = 0; db < 4; ++db) {
                int d4 = db * 4 + quad;
                *(f32x4*)&cO[(ql * 16 + (d4 ^ (ql & 15))) << 2] = o[db][nb];
            }
        }
    }
    __syncthreads();
    if (g == 0) {
#pragma unroll
        for (int nb = 0; nb < 2; ++nb) {
            int ql = ww * 32 + nb * 16 + c;
            int qq = qt * 128 + ql;
            float m2 = cml[ql], l2 = cml[128 + ql];
            float mm = fmaxf(m_i[nb], m2);
            float a1 = __builtin_amdgcn_exp2f(m_i[nb] - mm);
            float a2 = __builtin_amdgcn_exp2f(m2 - mm);
            float linv = 1.f / (l_i[nb] * a1 + l2 * a2);
#pragma unroll
            for (int db = 0; db < 4; ++db) {
                int d4 = db * 4 + quad;
                f32x4 v2 = *(const f32x4*)&cO[(ql * 16 + (d4 ^ (ql & 15))) << 2];
                f32x4 v = (o[db][nb] * a1 + v2 * a2) * linv;
                *(f32x4*)(out + ((size_t)b * S_ + qq) * H_ + hh * 64 + db * 16 + quad * 4) = v;
            }
        }
    }
}

// ---------------- launch ----------------
extern "C" void kernel_launch(void* const* d_in, const int* in_sizes, int n_in,
                              void* d_out, int out_size, void* d_ws, size_t ws_size,
                              hipStream_t stream) {
    const float* query = (const float*)d_in[0];
    const float* key   = (const float*)d_in[1];
    const float* value = (const float*)d_in[2];
    const float* mask  = (const float*)d_in[3];
    const float* Wq    = (const float*)d_in[4];
    const float* bq    = (const float*)d_in[5];
    const float* Wk    = (const float*)d_in[6];
    const float* bk    = (const float*)d_in[7];
    const float* Wv    = (const float*)d_in[8];
    const float* bv    = (const float*)d_in[9];
    float* out = (float*)d_out;

    f16* p = (f16*)d_ws;
    f16* xq = p; p += SZX; f16* xk = p; p += SZX; f16* xv = p; p += SZX;
    f16* wq = p; p += SZW; f16* wk = p; p += SZW; f16* wv = p; p += SZW;
    f16* q  = p; p += SZX; f16* k  = p; p += SZX; f16* vt = p; p += SZX;
    float* mask_s = (float*)p;   // B_*S_ floats

    const int total = 3 * (int)(SZX / 4) + 3 * (int)(SZW / 4) + (B_ * S_ / 4);
    prep_kernel<<<(total + 255) / 256, 256, 0, stream>>>(
        query, key, value, Wq, Wk, Wv, mask, xq, xk, xv, wq, wk, wv, mask_s);

    dim3 pg(24, M_ / 128);
    proj_kernel<<<pg, 256, 0, stream>>>(xq, xk, xv, wq, wk, wv, bq, bk, bv, q, k, vt);

    dim3 ag(S_ / 128, B_ * NH_);
    attn_kernel<<<ag, 512, 0, stream>>>(q, k, vt, mask_s, out);
}